// Round 10
// baseline (91.028 us; speedup 1.0000x reference)
//
#include <hip/hip_runtime.h>
#include <math.h>

#define B_   8
#define T_   128
#define C_   256
#define XLDS 264       // Xs row stride in ushorts (256 data + 8 pad; 132 dw -> 2-way free)
#define WLDP 136       // Ws row stride in ushorts (128 data + 8 pad)

typedef unsigned short ushort;
typedef ushort ushort8v __attribute__((ext_vector_type(8)));
typedef __bf16 bf16x8  __attribute__((ext_vector_type(8)));
typedef float  f32x4   __attribute__((ext_vector_type(4)));

__device__ __forceinline__ ushort f2bf(float f) {
    unsigned u = __float_as_uint(f);
    u += 0x7fffu + ((u >> 16) & 1u);     // RNE
    return (ushort)(u >> 16);
}

// gelu ~ x * sigmoid(1.59577x + 0.0713548x^3); exp2-folded, native v_exp_f32
__device__ __forceinline__ float gelu_fast(float x) {
    float x2 = x * x;
    float y2 = x * fmaf(-0.10294234f, x2, -2.30220818f);  // -y*log2(e)
    float e  = __builtin_amdgcn_exp2f(y2);
    return x * __builtin_amdgcn_rcpf(1.0f + e);
}

__device__ __forceinline__ ushort8v pack8(float4 lo, float4 hi) {
    ushort8v u;
    u[0] = f2bf(lo.x); u[1] = f2bf(lo.y); u[2] = f2bf(lo.z); u[3] = f2bf(lo.w);
    u[4] = f2bf(hi.x); u[5] = f2bf(hi.y); u[6] = f2bf(hi.z); u[7] = f2bf(hi.w);
    return u;
}

// ---------------------------------------------------------------------------
// W pack (one block per o): Wt[2][768][768] bf16:
//   Wt[0][o*3+kw][kh*256+ci] = W[o][ci][kh][kw]
//   Wt[1][o*3+kh][kw*256+ci] = W[o][256+ci][kh][kw]
// ---------------------------------------------------------------------------
__global__ __launch_bounds__(256) void tc_packw(
    const float* __restrict__ W, ushort* __restrict__ Wt)
{
    const int o = blockIdx.x, t = threadIdx.x;
    __shared__ ushort lw[4608];          // W[o] linear: [c 512][r 9]
    const float* src = W + (size_t)o * 4608;
    #pragma unroll
    for (int i = 0; i < 18; ++i)
        lw[t + i * 256] = f2bf(src[t + i * 256]);
    __syncthreads();
    #pragma unroll
    for (int i = 0; i < 18; ++i) {
        int d  = t + i * 256;            // 0..4607
        int s  = d / 2304;
        int e  = d - s * 2304;
        int nj = e / 768;                // kw (s=0) / kh (s=1)
        int k  = e - nj * 768;           // sh*256 + ci
        int sh = k >> 8, ci = k & 255;
        ushort v = (s == 0) ? lw[ci * 9 + sh * 3 + nj]
                            : lw[(256 + ci) * 9 + nj * 3 + sh];
        Wt[((size_t)s * 768 + o * 3 + nj) * 768 + k] = v;
    }
}

// ---------------------------------------------------------------------------
// Shift-fused GEMM: AB[s][n][m] = sum_sh sum_ci Xpad[s][m+sh-1][ci]*Wt[s][n][sh*256+ci]
// Block (tn 0..11, tm 0..31, s): M=32, N=64, K=768 as 6 rounds (sh x k-half).
// X staged from f32 (convert-on-stage) as 34 rows x 256 k, boundary rows zeroed;
// kh/kw shift = A-fragment row offset (+sh). W reg-prefetched per round.
// 768 blocks, 35.4 KB LDS -> 4 blocks/CU co-resident.
// ---------------------------------------------------------------------------
__global__ __launch_bounds__(256, 4) void tc_gemm(
    const float* __restrict__ x1, const float* __restrict__ x2,
    const ushort* __restrict__ Wt, float* __restrict__ AB)
{
    __shared__ ushort Xs[34 * XLDS];     // 17952 B
    __shared__ ushort Ws[64 * WLDP];     // 17408 B

    const int tn = blockIdx.x;           // 0..11
    const int tm = blockIdx.y;           // 0..31
    const int s  = blockIdx.z;
    const int u  = threadIdx.x;
    const int l  = u & 63, w = u >> 6;
    const int wr = w >> 1, wc = w & 1;   // m-half, n-half
    const int r16 = l & 15, kb = l >> 4;

    const int b_     = tm >> 2;
    const int t_base = (tm & 3) * 32;
    const float*  Xb = (s ? x2 : x1) + (size_t)b_ * T_ * C_;
    const ushort* Wb = Wt + ((size_t)s * 768 + tn * 64) * 768;

    // ---- stage X rows -1..32 (34 rows x 256 ci) from f32, zero out-of-batch
    {
        #pragma unroll
        for (int j = 0; j < 5; ++j) {
            int c = u + j * 256;
            if (j < 4 || c < 1088) {
                int i  = c >> 5;             // staged row 0..33
                int kc = (c & 31) * 8;
                int t  = t_base + i - 1;
                ushort8v v = {};
                if (t >= 0 && t < T_) {
                    const float* p = Xb + (size_t)t * C_ + kc;
                    v = pack8(*(const float4*)p, *(const float4*)(p + 4));
                }
                *(ushort8v*)&Xs[i * XLDS + kc] = v;
            }
        }
    }

    // ---- prefetch round 0 W tile (64 n x 128 k) into regs
    ushort8v wbuf[4];
    #pragma unroll
    for (int j = 0; j < 4; ++j) {
        int c = u + j * 256;
        wbuf[j] = *(const ushort8v*)(Wb + (size_t)(c >> 4) * 768 + (c & 15) * 8);
    }

    f32x4 acc[2] = {};
    #pragma unroll
    for (int r = 0; r < 6; ++r) {
        const int sh = r >> 1, p = r & 1;
        __syncthreads();                 // X staged / prior round's W frag reads done
        #pragma unroll
        for (int j = 0; j < 4; ++j) {
            int c = u + j * 256;
            *(ushort8v*)&Ws[(c >> 4) * WLDP + (c & 15) * 8] = wbuf[j];
        }
        if (r < 5) {
            const int rn = r + 1;
            const ushort* wsrc = Wb + (rn >> 1) * 256 + (rn & 1) * 128;
            #pragma unroll
            for (int j = 0; j < 4; ++j) {
                int c = u + j * 256;
                wbuf[j] = *(const ushort8v*)(wsrc + (size_t)(c >> 4) * 768 + (c & 15) * 8);
            }
        }
        __syncthreads();
        #pragma unroll
        for (int ks = 0; ks < 4; ++ks) {
            const int ka  = p * 128 + ks * 32 + kb * 8;
            const int kw_ = ks * 32 + kb * 8;
            bf16x8 a0 = __builtin_bit_cast(bf16x8,
                *(const ushort8v*)&Xs[(wr * 16 + r16 + sh) * XLDS + ka]);
            bf16x8 b0 = __builtin_bit_cast(bf16x8,
                *(const ushort8v*)&Ws[(wc * 32 + r16) * WLDP + kw_]);
            bf16x8 b1 = __builtin_bit_cast(bf16x8,
                *(const ushort8v*)&Ws[(wc * 32 + 16 + r16) * WLDP + kw_]);
            acc[0] = __builtin_amdgcn_mfma_f32_16x16x32_bf16(a0, b0, acc[0], 0, 0, 0);
            acc[1] = __builtin_amdgcn_mfma_f32_16x16x32_bf16(a0, b1, acc[1], 0, 0, 0);
        }
    }

    // ---- store AB[s][n][m]; D: col(n)=r16, row(m)=kb*4+reg (m-contiguous f32x4)
    #pragma unroll
    for (int j = 0; j < 2; ++j) {
        int n = tn * 64 + wc * 32 + j * 16 + r16;
        int m = tm * 32 + wr * 16 + kb * 4;
        *(f32x4*)&AB[((size_t)s * 768 + n) * 1024 + m] = acc[j];
    }
}

// ---------------------------------------------------------------------------
// Finalize: block (b, o), 128 threads = t.
//   a_j = AB[0][o*3+j][b*128+t]  (j = kw class; kh-shift folded in GEMM)
//   b_j = AB[1][o*3+j][b*128+t]  (j = kh class)
// ---------------------------------------------------------------------------
__global__ __launch_bounds__(128) void tc_fin(
    const float* __restrict__ AB, const float* __restrict__ x1,
    const float* __restrict__ bias, const float* __restrict__ alpha_p,
    float* __restrict__ out)
{
    const int o = blockIdx.x & 255;
    const int b = blockIdx.x >> 8;
    const int t = threadIdx.x;

    __shared__ float Bv[3][T_];

    const float* A0 = AB + ((size_t)o * 3) * 1024 + b * T_ + t;
    const float* A1 = AB + ((size_t)768 + o * 3) * 1024 + b * T_ + t;
    float a0 = A0[0], a1 = A0[1024], a2 = A0[2048];
    float b0 = A1[0], b1 = A1[1024], b2 = A1[2048];

    const float bo = bias[o];
    float A3 = bo + a0 + a1 + a2;                // interior t2
    float Al = bo + a1 + a2;                     // t2 == 0   (kw=0 invalid)
    float Ar = bo + a0 + a1;                     // t2 == T-1 (kw=2 invalid)
    Bv[0][t] = b0 + b1 + b2;                     // interior t1
    Bv[1][t] = b1 + b2;                          // t1 == 0   (kh=0 invalid)
    Bv[2][t] = b0 + b1;                          // t1 == T-1 (kh=2 invalid)
    __syncthreads();

    int cls = (t == 0) ? 1 : ((t == T_ - 1) ? 2 : 0);
    const float* Bs = Bv[cls];
    float s0 = 0.f, s1 = 0.f, s2 = 0.f, s3 = 0.f;
    for (int j = 0; j < T_; j += 4) {
        f32x4 v = *(const f32x4*)&Bs[j];
        s0 += gelu_fast(A3 + v[0]); s1 += gelu_fast(A3 + v[1]);
        s2 += gelu_fast(A3 + v[2]); s3 += gelu_fast(A3 + v[3]);
    }
    float sm = (s0 + s1) + (s2 + s3);
    float bl = Bs[0], br = Bs[T_ - 1];
    sm += gelu_fast(Al + bl) - gelu_fast(A3 + bl);
    sm += gelu_fast(Ar + br) - gelu_fast(A3 + br);

    const float kk2 = (*alpha_p) * (1.0f / (float)T_);
    size_t go = ((size_t)(b * T_ + t)) * C_ + o;
    out[go] = sm * kk2 + x1[go];
}

extern "C" void kernel_launch(void* const* d_in, const int* in_sizes, int n_in,
                              void* d_out, int out_size, void* d_ws, size_t ws_size,
                              hipStream_t stream) {
    const float* x1    = (const float*)d_in[0];
    const float* x2    = (const float*)d_in[1];
    const float* W     = (const float*)d_in[2];
    const float* bias  = (const float*)d_in[3];
    const float* alpha = (const float*)d_in[4];
    float* out = (float*)d_out;

    // ws: AB f32 [2][768][1024] = 6.29 MB | Wt bf16 [2][768][768] = 2.36 MB
    float*  AB = (float*)d_ws;
    ushort* Wt = (ushort*)((char*)d_ws + (size_t)2 * 768 * 1024 * 4);

    tc_packw<<<256, 256, 0, stream>>>(W, Wt);
    tc_gemm<<<dim3(12, 32, 2), 256, 0, stream>>>(x1, x2, Wt, AB);
    tc_fin<<<B_ * C_, T_, 0, stream>>>(AB, x1, bias, alpha, out);
}

// Round 11
// 90.736 us; speedup vs baseline: 1.0032x; 1.0032x over previous
//
#include <hip/hip_runtime.h>
#include <math.h>

#define B_   8
#define T_   128
#define C_   256
#define XLDS 264       // Xs row stride in ushorts (256 data + 8 pad; 132 dw -> 2-way free)
#define WLDP 136       // Ws row stride in ushorts (128 data + 8 pad)

typedef unsigned short ushort;
typedef ushort ushort8v __attribute__((ext_vector_type(8)));
typedef __bf16 bf16x8  __attribute__((ext_vector_type(8)));
typedef float  f32x4   __attribute__((ext_vector_type(4)));

__device__ __forceinline__ ushort f2bf(float f) {
    unsigned u = __float_as_uint(f);
    u += 0x7fffu + ((u >> 16) & 1u);     // RNE
    return (ushort)(u >> 16);
}

// gelu ~ x * sigmoid(1.59577x + 0.0713548x^3); exp2-folded, native v_exp_f32
__device__ __forceinline__ float gelu_fast(float x) {
    float x2 = x * x;
    float y2 = x * fmaf(-0.10294234f, x2, -2.30220818f);  // -y*log2(e)
    float e  = __builtin_amdgcn_exp2f(y2);
    return x * __builtin_amdgcn_rcpf(1.0f + e);
}

__device__ __forceinline__ ushort8v pack8(float4 lo, float4 hi) {
    ushort8v u;
    u[0] = f2bf(lo.x); u[1] = f2bf(lo.y); u[2] = f2bf(lo.z); u[3] = f2bf(lo.w);
    u[4] = f2bf(hi.x); u[5] = f2bf(hi.y); u[6] = f2bf(hi.z); u[7] = f2bf(hi.w);
    return u;
}

// ---------------------------------------------------------------------------
// W pack (one block per o): Wt[2][768][768] bf16:
//   Wt[0][o*3+kw][kh*256+ci] = W[o][ci][kh][kw]
//   Wt[1][o*3+kh][kw*256+ci] = W[o][256+ci][kh][kw]
// ---------------------------------------------------------------------------
__global__ __launch_bounds__(256) void tc_packw(
    const float* __restrict__ W, ushort* __restrict__ Wt)
{
    const int o = blockIdx.x, t = threadIdx.x;
    __shared__ ushort lw[4608];          // W[o] linear: [c 512][r 9]
    const float* src = W + (size_t)o * 4608;
    #pragma unroll
    for (int i = 0; i < 18; ++i)
        lw[t + i * 256] = f2bf(src[t + i * 256]);
    __syncthreads();
    #pragma unroll
    for (int i = 0; i < 18; ++i) {
        int d  = t + i * 256;            // 0..4607
        int s  = d / 2304;
        int e  = d - s * 2304;
        int nj = e / 768;                // kw (s=0) / kh (s=1)
        int k  = e - nj * 768;           // sh*256 + ci
        int sh = k >> 8, ci = k & 255;
        ushort v = (s == 0) ? lw[ci * 9 + sh * 3 + nj]
                            : lw[(256 + ci) * 9 + nj * 3 + sh];
        Wt[((size_t)s * 768 + o * 3 + nj) * 768 + k] = v;
    }
}

// ---------------------------------------------------------------------------
// Shift-fused GEMM: AB[s][n][m] = sum_sh sum_ci Xpad[s][m+sh-1][ci]*Wt[s][n][sh*256+ci]
// Block (tn 0..11, tm 0..15, s): M=64, N=64, K=768 as 6 rounds (sh x k-half).
// X staged ONCE from f32 (convert-on-stage) as 66 rows x 256 k (stride 264,
// batch-boundary rows zeroed); kh/kw shift = A-fragment row offset (+sh).
// W reg-prefetched per round. 384 blocks, 52.2 KB LDS -> 3 blocks/CU.
// ---------------------------------------------------------------------------
__global__ __launch_bounds__(256, 3) void tc_gemm(
    const float* __restrict__ x1, const float* __restrict__ x2,
    const ushort* __restrict__ Wt, float* __restrict__ AB)
{
    __shared__ ushort Xs[66 * XLDS];     // 34848 B
    __shared__ ushort Ws[64 * WLDP];     // 17408 B

    const int tn = blockIdx.x;           // 0..11
    const int tm = blockIdx.y;           // 0..15
    const int s  = blockIdx.z;
    const int u  = threadIdx.x;
    const int l  = u & 63, w = u >> 6;
    const int wr = w >> 1, wc = w & 1;
    const int r16 = l & 15, kb = l >> 4;

    const int b_     = tm >> 1;
    const int t_base = (tm & 1) * 64;
    const float*  Xb = (s ? x2 : x1) + (size_t)b_ * T_ * C_;
    const ushort* Wb = Wt + ((size_t)s * 768 + tn * 64) * 768;

    // ---- stage X rows -1..64 (66 rows x 256 ci) from f32, zero out-of-batch
    {
        #pragma unroll
        for (int j = 0; j < 9; ++j) {
            int c = u + j * 256;
            if (j < 8 || c < 2112) {
                int i  = c >> 5;             // staged row 0..65
                int kc = (c & 31) * 8;
                int t  = t_base + i - 1;
                ushort8v v = {};
                if (t >= 0 && t < T_) {
                    const float* p = Xb + (size_t)t * C_ + kc;
                    v = pack8(*(const float4*)p, *(const float4*)(p + 4));
                }
                *(ushort8v*)&Xs[i * XLDS + kc] = v;
            }
        }
    }

    // ---- prefetch round 0 W tile (64 n x 128 k) into regs
    ushort8v wbuf[4];
    #pragma unroll
    for (int j = 0; j < 4; ++j) {
        int c = u + j * 256;
        wbuf[j] = *(const ushort8v*)(Wb + (size_t)(c >> 4) * 768 + (c & 15) * 8);
    }

    f32x4 acc[2][2] = {};
    #pragma unroll
    for (int r = 0; r < 6; ++r) {
        const int sh = r >> 1, p = r & 1;
        __syncthreads();                 // X staged / prior round's W frag reads done
        #pragma unroll
        for (int j = 0; j < 4; ++j) {
            int c = u + j * 256;
            *(ushort8v*)&Ws[(c >> 4) * WLDP + (c & 15) * 8] = wbuf[j];
        }
        if (r < 5) {
            const int rn = r + 1;
            const ushort* wsrc = Wb + (rn >> 1) * 256 + (rn & 1) * 128;
            #pragma unroll
            for (int j = 0; j < 4; ++j) {
                int c = u + j * 256;
                wbuf[j] = *(const ushort8v*)(wsrc + (size_t)(c >> 4) * 768 + (c & 15) * 8);
            }
        }
        __syncthreads();
        #pragma unroll
        for (int ks = 0; ks < 4; ++ks) {
            const int ka  = p * 128 + ks * 32 + kb * 8;
            const int kw_ = ks * 32 + kb * 8;
            bf16x8 a0 = __builtin_bit_cast(bf16x8,
                *(const ushort8v*)&Xs[(wr * 32 + r16 + sh) * XLDS + ka]);
            bf16x8 a1 = __builtin_bit_cast(bf16x8,
                *(const ushort8v*)&Xs[(wr * 32 + 16 + r16 + sh) * XLDS + ka]);
            bf16x8 b0 = __builtin_bit_cast(bf16x8,
                *(const ushort8v*)&Ws[(wc * 32 + r16) * WLDP + kw_]);
            bf16x8 b1 = __builtin_bit_cast(bf16x8,
                *(const ushort8v*)&Ws[(wc * 32 + 16 + r16) * WLDP + kw_]);
            acc[0][0] = __builtin_amdgcn_mfma_f32_16x16x32_bf16(a0, b0, acc[0][0], 0, 0, 0);
            acc[0][1] = __builtin_amdgcn_mfma_f32_16x16x32_bf16(a0, b1, acc[0][1], 0, 0, 0);
            acc[1][0] = __builtin_amdgcn_mfma_f32_16x16x32_bf16(a1, b0, acc[1][0], 0, 0, 0);
            acc[1][1] = __builtin_amdgcn_mfma_f32_16x16x32_bf16(a1, b1, acc[1][1], 0, 0, 0);
        }
    }

    // ---- store AB[s][n][m]; D: col(n)=r16, row(m)=kb*4+reg (m-contiguous f32x4)
    #pragma unroll
    for (int j = 0; j < 2; ++j) {
        int n = tn * 64 + wc * 32 + j * 16 + r16;
        #pragma unroll
        for (int i = 0; i < 2; ++i) {
            int m = tm * 64 + wr * 32 + i * 16 + kb * 4;
            *(f32x4*)&AB[((size_t)s * 768 + n) * 1024 + m] = acc[i][j];
        }
    }
}

// ---------------------------------------------------------------------------
// Finalize: block handles 2 (b,o) pairs, 256 threads (pair p = tid>>7, t = tid&127).
//   a_j = AB[0][o*3+j][b*128+t]  (j = kw class; kh-shift folded in GEMM)
//   b_j = AB[1][o*3+j][b*128+t]  (j = kh class)
// ---------------------------------------------------------------------------
__global__ __launch_bounds__(256) void tc_fin(
    const float* __restrict__ AB, const float* __restrict__ x1,
    const float* __restrict__ bias, const float* __restrict__ alpha_p,
    float* __restrict__ out)
{
    const int p   = threadIdx.x >> 7;
    const int t   = threadIdx.x & 127;
    const int idx = blockIdx.x * 2 + p;
    const int o   = idx & 255;
    const int b   = idx >> 8;

    __shared__ float Bv[2][3][T_];

    const float* A0 = AB + ((size_t)o * 3) * 1024 + b * T_ + t;
    const float* A1 = AB + ((size_t)768 + o * 3) * 1024 + b * T_ + t;
    float a0 = A0[0], a1 = A0[1024], a2 = A0[2048];
    float b0 = A1[0], b1 = A1[1024], b2 = A1[2048];

    const float bo = bias[o];
    float A3 = bo + a0 + a1 + a2;                // interior t2
    float Al = bo + a1 + a2;                     // t2 == 0   (kw=0 invalid)
    float Ar = bo + a0 + a1;                     // t2 == T-1 (kw=2 invalid)
    Bv[p][0][t] = b0 + b1 + b2;                  // interior t1
    Bv[p][1][t] = b1 + b2;                       // t1 == 0   (kh=0 invalid)
    Bv[p][2][t] = b0 + b1;                       // t1 == T-1 (kh=2 invalid)
    __syncthreads();

    int cls = (t == 0) ? 1 : ((t == T_ - 1) ? 2 : 0);
    const float* Bs = Bv[p][cls];
    float s0 = 0.f, s1 = 0.f, s2 = 0.f, s3 = 0.f;
    for (int j = 0; j < T_; j += 4) {
        f32x4 v = *(const f32x4*)&Bs[j];
        s0 += gelu_fast(A3 + v[0]); s1 += gelu_fast(A3 + v[1]);
        s2 += gelu_fast(A3 + v[2]); s3 += gelu_fast(A3 + v[3]);
    }
    float sm = (s0 + s1) + (s2 + s3);
    float bl = Bs[0], br = Bs[T_ - 1];
    sm += gelu_fast(Al + bl) - gelu_fast(A3 + bl);
    sm += gelu_fast(Ar + br) - gelu_fast(A3 + br);

    const float kk2 = (*alpha_p) * (1.0f / (float)T_);
    size_t go = ((size_t)(b * T_ + t)) * C_ + o;
    out[go] = sm * kk2 + x1[go];
}

extern "C" void kernel_launch(void* const* d_in, const int* in_sizes, int n_in,
                              void* d_out, int out_size, void* d_ws, size_t ws_size,
                              hipStream_t stream) {
    const float* x1    = (const float*)d_in[0];
    const float* x2    = (const float*)d_in[1];
    const float* W     = (const float*)d_in[2];
    const float* bias  = (const float*)d_in[3];
    const float* alpha = (const float*)d_in[4];
    float* out = (float*)d_out;

    // ws: AB f32 [2][768][1024] = 6.29 MB | Wt bf16 [2][768][768] = 2.36 MB
    float*  AB = (float*)d_ws;
    ushort* Wt = (ushort*)((char*)d_ws + (size_t)2 * 768 * 1024 * 4);

    tc_packw<<<256, 256, 0, stream>>>(W, Wt);
    tc_gemm<<<dim3(12, 16, 2), 256, 0, stream>>>(x1, x2, Wt, AB);
    tc_fin<<<B_ * C_ / 2, 256, 0, stream>>>(AB, x1, bias, alpha, out);
}

// Round 12
// 85.643 us; speedup vs baseline: 1.0629x; 1.0595x over previous
//
#include <hip/hip_runtime.h>
#include <math.h>

#define B_   8
#define T_   128
#define C_   256
#define XLDS 264       // Xs row stride in ushorts (256 data + 8 pad; 132 dw -> 2-way free)
#define WLDP 136       // Ws row stride in ushorts (128 data + 8 pad)

typedef unsigned short ushort;
typedef ushort ushort8v __attribute__((ext_vector_type(8)));
typedef __bf16 bf16x8  __attribute__((ext_vector_type(8)));
typedef float  f32x4   __attribute__((ext_vector_type(4)));

__device__ __forceinline__ ushort f2bf(float f) {
    unsigned u = __float_as_uint(f);
    u += 0x7fffu + ((u >> 16) & 1u);     // RNE
    return (ushort)(u >> 16);
}

// gelu ~ x * sigmoid(1.59577x + 0.0713548x^3); exp2-folded, native v_exp_f32
__device__ __forceinline__ float gelu_fast(float x) {
    float x2 = x * x;
    float y2 = x * fmaf(-0.10294234f, x2, -2.30220818f);  // -y*log2(e)
    float e  = __builtin_amdgcn_exp2f(y2);
    return x * __builtin_amdgcn_rcpf(1.0f + e);
}

__device__ __forceinline__ ushort8v pack8(float4 lo, float4 hi) {
    ushort8v u;
    u[0] = f2bf(lo.x); u[1] = f2bf(lo.y); u[2] = f2bf(lo.z); u[3] = f2bf(lo.w);
    u[4] = f2bf(hi.x); u[5] = f2bf(hi.y); u[6] = f2bf(hi.z); u[7] = f2bf(hi.w);
    return u;
}

// ---------------------------------------------------------------------------
// W pack (one block per o): Wt[2][768][768] bf16:
//   Wt[0][o*3+kw][kh*256+ci] = W[o][ci][kh][kw]
//   Wt[1][o*3+kh][kw*256+ci] = W[o][256+ci][kh][kw]
// ---------------------------------------------------------------------------
__global__ __launch_bounds__(256) void tc_packw(
    const float* __restrict__ W, ushort* __restrict__ Wt)
{
    const int o = blockIdx.x, t = threadIdx.x;
    __shared__ ushort lw[4608];          // W[o] linear: [c 512][r 9]
    const float* src = W + (size_t)o * 4608;
    #pragma unroll
    for (int i = 0; i < 18; ++i)
        lw[t + i * 256] = f2bf(src[t + i * 256]);
    __syncthreads();
    #pragma unroll
    for (int i = 0; i < 18; ++i) {
        int d  = t + i * 256;            // 0..4607
        int s  = d / 2304;
        int e  = d - s * 2304;
        int nj = e / 768;                // kw (s=0) / kh (s=1)
        int k  = e - nj * 768;           // sh*256 + ci
        int sh = k >> 8, ci = k & 255;
        ushort v = (s == 0) ? lw[ci * 9 + sh * 3 + nj]
                            : lw[(256 + ci) * 9 + nj * 3 + sh];
        Wt[((size_t)s * 768 + o * 3 + nj) * 768 + k] = v;
    }
}

// ---------------------------------------------------------------------------
// Shift-fused GEMM (verified R9/R11): AB[s][n][m] =
//   sum_sh sum_ci Xpad[s][m+sh-1][ci] * Wt[s][n][sh*256+ci]
// Block (tn, tm, s): M=64, N=64, K=768 as 6 rounds (sh x k-half).
// ---------------------------------------------------------------------------
__global__ __launch_bounds__(256, 3) void tc_gemm(
    const float* __restrict__ x1, const float* __restrict__ x2,
    const ushort* __restrict__ Wt, float* __restrict__ AB)
{
    __shared__ ushort Xs[66 * XLDS];     // 34848 B
    __shared__ ushort Ws[64 * WLDP];     // 17408 B

    const int tn = blockIdx.x;           // 0..11
    const int tm = blockIdx.y;           // 0..15
    const int s  = blockIdx.z;
    const int u  = threadIdx.x;
    const int l  = u & 63, w = u >> 6;
    const int wr = w >> 1, wc = w & 1;
    const int r16 = l & 15, kb = l >> 4;

    const int b_     = tm >> 1;
    const int t_base = (tm & 1) * 64;
    const float*  Xb = (s ? x2 : x1) + (size_t)b_ * T_ * C_;
    const ushort* Wb = Wt + ((size_t)s * 768 + tn * 64) * 768;

    // ---- stage X rows -1..64 (66 rows x 256 ci) from f32, zero out-of-batch
    {
        #pragma unroll
        for (int j = 0; j < 9; ++j) {
            int c = u + j * 256;
            if (j < 8 || c < 2112) {
                int i  = c >> 5;             // staged row 0..65
                int kc = (c & 31) * 8;
                int t  = t_base + i - 1;
                ushort8v v = {};
                if (t >= 0 && t < T_) {
                    const float* p = Xb + (size_t)t * C_ + kc;
                    v = pack8(*(const float4*)p, *(const float4*)(p + 4));
                }
                *(ushort8v*)&Xs[i * XLDS + kc] = v;
            }
        }
    }

    // ---- prefetch round 0 W tile (64 n x 128 k) into regs
    ushort8v wbuf[4];
    #pragma unroll
    for (int j = 0; j < 4; ++j) {
        int c = u + j * 256;
        wbuf[j] = *(const ushort8v*)(Wb + (size_t)(c >> 4) * 768 + (c & 15) * 8);
    }

    f32x4 acc[2][2] = {};
    #pragma unroll
    for (int r = 0; r < 6; ++r) {
        const int sh = r >> 1, p = r & 1;
        __syncthreads();                 // X staged / prior round's W frag reads done
        #pragma unroll
        for (int j = 0; j < 4; ++j) {
            int c = u + j * 256;
            *(ushort8v*)&Ws[(c >> 4) * WLDP + (c & 15) * 8] = wbuf[j];
        }
        if (r < 5) {
            const int rn = r + 1;
            const ushort* wsrc = Wb + (rn >> 1) * 256 + (rn & 1) * 128;
            #pragma unroll
            for (int j = 0; j < 4; ++j) {
                int c = u + j * 256;
                wbuf[j] = *(const ushort8v*)(wsrc + (size_t)(c >> 4) * 768 + (c & 15) * 8);
            }
        }
        __syncthreads();
        #pragma unroll
        for (int ks = 0; ks < 4; ++ks) {
            const int ka  = p * 128 + ks * 32 + kb * 8;
            const int kw_ = ks * 32 + kb * 8;
            bf16x8 a0 = __builtin_bit_cast(bf16x8,
                *(const ushort8v*)&Xs[(wr * 32 + r16 + sh) * XLDS + ka]);
            bf16x8 a1 = __builtin_bit_cast(bf16x8,
                *(const ushort8v*)&Xs[(wr * 32 + 16 + r16 + sh) * XLDS + ka]);
            bf16x8 b0 = __builtin_bit_cast(bf16x8,
                *(const ushort8v*)&Ws[(wc * 32 + r16) * WLDP + kw_]);
            bf16x8 b1 = __builtin_bit_cast(bf16x8,
                *(const ushort8v*)&Ws[(wc * 32 + 16 + r16) * WLDP + kw_]);
            acc[0][0] = __builtin_amdgcn_mfma_f32_16x16x32_bf16(a0, b0, acc[0][0], 0, 0, 0);
            acc[0][1] = __builtin_amdgcn_mfma_f32_16x16x32_bf16(a0, b1, acc[0][1], 0, 0, 0);
            acc[1][0] = __builtin_amdgcn_mfma_f32_16x16x32_bf16(a1, b0, acc[1][0], 0, 0, 0);
            acc[1][1] = __builtin_amdgcn_mfma_f32_16x16x32_bf16(a1, b1, acc[1][1], 0, 0, 0);
        }
    }

    // ---- store AB[s][n][m]; D: col(n)=r16, row(m)=kb*4+reg (m-contiguous f32x4)
    #pragma unroll
    for (int j = 0; j < 2; ++j) {
        int n = tn * 64 + wc * 32 + j * 16 + r16;
        #pragma unroll
        for (int i = 0; i < 2; ++i) {
            int m = tm * 64 + wr * 32 + i * 16 + kb * 4;
            *(f32x4*)&AB[((size_t)s * 768 + n) * 1024 + m] = acc[i][j];
        }
    }
}

// ---------------------------------------------------------------------------
// Finalize with table-interpolated gelu-sum. Block (b,o), 128 threads = t.
// Interior t1: f(A) = sum_t2 gelu(A + Bv0[t2]) is a smooth 1-D function of A;
// build F on 32 nodes over [Amin,Amax] cooperatively, lerp per t1, then apply
// the 4 endpoint corrections exactly. Edge rows (t1=0,127; different B-vecs)
// are evaluated directly, distributed 1 t2/thread + shuffle reduction.
// Lerp error bound: (dA/31)^2/8 * sum|gelu''| * alpha/T  <~ 2e-3 in output.
// ---------------------------------------------------------------------------
__global__ __launch_bounds__(128) void tc_fin(
    const float* __restrict__ AB, const float* __restrict__ x1,
    const float* __restrict__ bias, const float* __restrict__ alpha_p,
    float* __restrict__ out)
{
    const int o = blockIdx.x & 255;
    const int b = blockIdx.x >> 8;
    const int t = threadIdx.x;

    __shared__ float Bv[3][T_];
    __shared__ float Aa3[T_], Aal[T_], Aar[T_];
    __shared__ float Part[4][32];
    __shared__ float Ftab[32];
    __shared__ float Red[4];
    __shared__ float EdgeR[4];

    const float* A0 = AB + ((size_t)o * 3) * 1024 + b * T_ + t;
    const float* A1 = AB + ((size_t)768 + o * 3) * 1024 + b * T_ + t;
    float a0 = A0[0], a1 = A0[1024], a2 = A0[2048];
    float b0 = A1[0], b1 = A1[1024], b2 = A1[2048];

    const float bo = bias[o];
    const float A3 = bo + a0 + a1 + a2;          // interior t2
    const float Al = bo + a1 + a2;               // t2 == 0   (kw=0 invalid)
    const float Ar = bo + a0 + a1;               // t2 == T-1 (kw=2 invalid)
    Aa3[t] = A3; Aal[t] = Al; Aar[t] = Ar;
    Bv[0][t] = b0 + b1 + b2;                     // interior t1
    Bv[1][t] = b1 + b2;                          // t1 == 0   (kh=0 invalid)
    Bv[2][t] = b0 + b1;                          // t1 == T-1 (kh=2 invalid)

    // per-wave min/max of A3
    float mn = A3, mx = A3;
    #pragma unroll
    for (int d = 1; d < 64; d <<= 1) {
        mn = fminf(mn, __shfl_xor(mn, d));
        mx = fmaxf(mx, __shfl_xor(mx, d));
    }
    if ((t & 63) == 0) { Red[t >> 6] = mn; Red[2 + (t >> 6)] = mx; }
    __syncthreads();                             // B1

    const float Amin = fminf(Red[0], Red[1]);
    const float Amax = fmaxf(Red[2], Red[3]);
    float h = fmaxf((Amax - Amin) * (1.0f / 31.0f), 1e-12f);
    const float hinv = 1.0f / h;

    // ---- table build: node n = t&31, t2-quarter q = t>>5 (32 gelus/thread)
    {
        const int n = t & 31, q = t >> 5;
        const float node = fmaf(h, (float)n, Amin);
        const float* Bq = &Bv[0][q * 32];
        float p0 = 0.f, p1 = 0.f, p2 = 0.f, p3 = 0.f;
        #pragma unroll
        for (int j = 0; j < 32; j += 4) {
            p0 += gelu_fast(node + Bq[j]);
            p1 += gelu_fast(node + Bq[j + 1]);
            p2 += gelu_fast(node + Bq[j + 2]);
            p3 += gelu_fast(node + Bq[j + 3]);
        }
        Part[q][n] = (p0 + p1) + (p2 + p3);
    }

    // ---- edge rows (t1=0 uses Bv1, t1=127 uses Bv2): thread t plays t2 role
    {
        float za = (t == 0) ? Aal[0]   : ((t == T_ - 1) ? Aar[0]   : Aa3[0]);
        float zb = (t == 0) ? Aal[127] : ((t == T_ - 1) ? Aar[127] : Aa3[127]);
        float e0 = gelu_fast(za + Bv[1][t]);
        float e1 = gelu_fast(zb + Bv[2][t]);
        #pragma unroll
        for (int d = 1; d < 64; d <<= 1) {
            e0 += __shfl_xor(e0, d);
            e1 += __shfl_xor(e1, d);
        }
        if ((t & 63) == 0) { EdgeR[t >> 6] = e0; EdgeR[2 + (t >> 6)] = e1; }
    }
    __syncthreads();                             // B2

    if (t < 32) Ftab[t] = (Part[0][t] + Part[1][t]) + (Part[2][t] + Part[3][t]);
    __syncthreads();                             // B3

    float sm;
    if (t == 0)            sm = EdgeR[0] + EdgeR[1];
    else if (t == T_ - 1)  sm = EdgeR[2] + EdgeR[3];
    else {
        float idx = (A3 - Amin) * hinv;
        int   i   = (int)idx;
        i = i < 0 ? 0 : (i > 30 ? 30 : i);
        float fr  = idx - (float)i;
        float f   = fmaf(fr, Ftab[i + 1] - Ftab[i], Ftab[i]);
        // exact endpoint corrections (t2 = 0 and T-1)
        float B0 = Bv[0][0], B127 = Bv[0][T_ - 1];
        f += gelu_fast(Al + B0)   - gelu_fast(A3 + B0)
           + gelu_fast(Ar + B127) - gelu_fast(A3 + B127);
        sm = f;
    }

    const float kk2 = (*alpha_p) * (1.0f / (float)T_);
    size_t go = ((size_t)(b * T_ + t)) * C_ + o;
    out[go] = sm * kk2 + x1[go];
}

extern "C" void kernel_launch(void* const* d_in, const int* in_sizes, int n_in,
                              void* d_out, int out_size, void* d_ws, size_t ws_size,
                              hipStream_t stream) {
    const float* x1    = (const float*)d_in[0];
    const float* x2    = (const float*)d_in[1];
    const float* W     = (const float*)d_in[2];
    const float* bias  = (const float*)d_in[3];
    const float* alpha = (const float*)d_in[4];
    float* out = (float*)d_out;

    // ws: AB f32 [2][768][1024] = 6.29 MB | Wt bf16 [2][768][768] = 2.36 MB
    float*  AB = (float*)d_ws;
    ushort* Wt = (ushort*)((char*)d_ws + (size_t)2 * 768 * 1024 * 4);

    tc_packw<<<256, 256, 0, stream>>>(W, Wt);
    tc_gemm<<<dim3(12, 16, 2), 256, 0, stream>>>(x1, x2, Wt, AB);
    tc_fin<<<B_ * C_, T_, 0, stream>>>(AB, x1, bias, alpha, out);
}